// Round 1
// baseline (2539.825 us; speedup 1.0000x reference)
//
#include <hip/hip_runtime.h>
#include <hip/hip_bf16.h>

// Problem constants
#define NSAMP 131072
#define TA    90      // T*A
#define HID   128
#define DLAT  512
#define G     4
#define K     32
#define NC    128     // G*K

// d_out layout (float elements): quant[N*512], code[N*4], recon[N*90], loss[1]
#define OFF_CODE  67108864ll
#define OFF_RECON (67108864ll + 524288ll)
#define OFF_LOSS  (67108864ll + 524288ll + 11796480ll)

// ---------------------------------------------------------------------------
// K0: code-Gram table P[c1*128+c2] = e_c1 . e_c2  (diag = ||e||^2). 64KB in ws.
// ---------------------------------------------------------------------------
__global__ void k_ptable(const float* __restrict__ cb, float* __restrict__ P) {
    int gid = blockIdx.x * blockDim.x + threadIdx.x;   // 16384 threads
    int c1 = gid >> 7, c2 = gid & 127;
    const float4* a = (const float4*)(cb + (long long)c1 * DLAT);
    const float4* b = (const float4*)(cb + (long long)c2 * DLAT);
    float s = 0.f;
    for (int i = 0; i < DLAT / 4; ++i) {
        float4 x = a[i], y = b[i];
        s += x.x * y.x + x.y * y.y + x.z * y.z + x.w * y.w;
    }
    P[gid] = s;
}

// ---------------------------------------------------------------------------
// K1: fused encoder + residual-VQ argmin + loss partials + code output.
// One thread per sample; weights via wave-uniform loads (SGPR path);
// h1/h2 live in a per-thread LDS column (dynamic j-index without scratch).
// ---------------------------------------------------------------------------
__launch_bounds__(64, 1)
__global__ void k_encvq(const float* __restrict__ X,
                        const float* __restrict__ w1, const float* __restrict__ b1,
                        const float* __restrict__ w2, const float* __restrict__ b2,
                        const float* __restrict__ w3, const float* __restrict__ b3,
                        const float* __restrict__ cb, const float* __restrict__ P,
                        float* __restrict__ codes_out, float* __restrict__ loss_acc) {
    __shared__ float act[HID * 64];                    // 32 KB, column t per thread
    const int t = threadIdx.x;
    const long long row = (long long)blockIdx.x * 64 + t;
    const float* xr = X + row * TA;

    float h[HID];
    // ---- E1: h1 = relu(x @ w1 + b1)
#pragma unroll
    for (int o = 0; o < HID; ++o) h[o] = b1[o];
    for (int j = 0; j < TA; ++j) {
        float xj = xr[j];
        const float* wr = w1 + j * HID;
#pragma unroll
        for (int o = 0; o < HID; ++o) h[o] = fmaf(xj, wr[o], h[o]);
    }
#pragma unroll
    for (int o = 0; o < HID; ++o) act[o * 64 + t] = fmaxf(h[o], 0.f);

    // ---- E2: h2 = relu(h1 @ w2 + b2)
#pragma unroll
    for (int o = 0; o < HID; ++o) h[o] = b2[o];
    for (int j = 0; j < HID; ++j) {
        float hj = act[j * 64 + t];
        const float* wr = w2 + j * HID;
#pragma unroll
        for (int o = 0; o < HID; ++o) h[o] = fmaf(hj, wr[o], h[o]);
    }
#pragma unroll
    for (int o = 0; o < HID; ++o) act[o * 64 + t] = fmaxf(h[o], 0.f);

    // ---- E3: z in chunks of 32, scored against all 128 codes on the fly.
    float zdot[NC];
#pragma unroll
    for (int c = 0; c < NC; ++c) zdot[c] = 0.f;
    float znorm = 0.f;
    for (int ch = 0; ch < 16; ++ch) {
        float z[32];
#pragma unroll
        for (int d = 0; d < 32; ++d) z[d] = b3[ch * 32 + d];
        for (int j = 0; j < HID; ++j) {
            float hj = act[j * 64 + t];
            const float* wr = w3 + j * DLAT + ch * 32;
#pragma unroll
            for (int d = 0; d < 32; ++d) z[d] = fmaf(hj, wr[d], z[d]);
        }
#pragma unroll
        for (int d = 0; d < 32; ++d) znorm = fmaf(z[d], z[d], znorm);
#pragma unroll
        for (int c = 0; c < NC; ++c) {
            const float* er = cb + c * DLAT + ch * 32;
            float tmp = 0.f;
#pragma unroll
            for (int d = 0; d < 32; ++d) tmp = fmaf(z[d], er[d], tmp);
            zdot[c] += tmp;
        }
    }

    // ---- Residual-VQ argmin chain (first-min tie-break = strict <, ascending k)
    float S1 = 0.f, Sp = 0.f;
    int cs[G];
    float lsum[G];
#pragma unroll
    for (int g = 0; g < G; ++g) {
        float best = 3.4e38f;
        int bi = g * K;
        float bzd = 0.f, bnrm = 0.f, bacc = 0.f;
#pragma unroll
        for (int k = 0; k < K; ++k) {
            int c = g * K + k;
            float nr = P[c * NC + c];                       // uniform → s_load
            float acc = 0.f;
#pragma unroll
            for (int gp = 0; gp < g; ++gp) acc += P[cs[gp] * NC + c];  // per-lane gather
            float dist = nr - 2.f * (zdot[c] - acc);
            if (dist < best) { best = dist; bi = c; bzd = zdot[c]; bnrm = nr; bacc = acc; }
        }
        cs[g] = bi;
        S1 += bzd;
        Sp += bnrm + 2.f * bacc;
        lsum[g] = znorm - 2.f * S1 + Sp;                    // ||r_after_g||^2
        codes_out[row * 4 + g] = (float)(bi - g * K);
    }

    // ---- per-wave loss reduction → 4 atomics/block
#pragma unroll
    for (int g = 0; g < G; ++g) {
        float v = lsum[g];
#pragma unroll
        for (int off = 32; off > 0; off >>= 1) v += __shfl_down(v, off);
        if (t == 0) atomicAdd(&loss_acc[g], v);
    }
}

// ---------------------------------------------------------------------------
// K2: quant construction (gather of 4 codebook rows) + fused fp32 decoder.
// ---------------------------------------------------------------------------
__launch_bounds__(64, 1)
__global__ void k_dec(const float* __restrict__ codes_f, const float* __restrict__ cb,
                      const float* __restrict__ w1, const float* __restrict__ b1,
                      const float* __restrict__ w2, const float* __restrict__ b2,
                      const float* __restrict__ w3, const float* __restrict__ b3,
                      float* __restrict__ quant_out, float* __restrict__ recon_out) {
    __shared__ float act[HID * 64];                    // 32 KB
    const int t = threadIdx.x;
    const long long row = (long long)blockIdx.x * 64 + t;

    int i0 = (int)codes_f[row * 4 + 0];
    int i1 = (int)codes_f[row * 4 + 1];
    int i2 = (int)codes_f[row * 4 + 2];
    int i3 = (int)codes_f[row * 4 + 3];
    const float* e0 = cb + (long long)(0 * K + i0) * DLAT;
    const float* e1 = cb + (long long)(1 * K + i1) * DLAT;
    const float* e2 = cb + (long long)(2 * K + i2) * DLAT;
    const float* e3 = cb + (long long)(3 * K + i3) * DLAT;
    float* qrow = quant_out + row * DLAT;

    float h[HID];
#pragma unroll
    for (int o = 0; o < HID; ++o) h[o] = b1[o];
    for (int ch = 0; ch < 16; ++ch) {
        float q[32];
#pragma unroll
        for (int v4 = 0; v4 < 8; ++v4) {
            int dbase = ch * 32 + v4 * 4;
            float4 a = *(const float4*)(e0 + dbase);
            float4 b = *(const float4*)(e1 + dbase);
            float4 c = *(const float4*)(e2 + dbase);
            float4 d = *(const float4*)(e3 + dbase);
            float4 s;
            s.x = a.x + b.x + c.x + d.x;
            s.y = a.y + b.y + c.y + d.y;
            s.z = a.z + b.z + c.z + d.z;
            s.w = a.w + b.w + c.w + d.w;
            *(float4*)(qrow + dbase) = s;              // quant output (fp32 exact)
            q[v4 * 4 + 0] = s.x; q[v4 * 4 + 1] = s.y;
            q[v4 * 4 + 2] = s.z; q[v4 * 4 + 3] = s.w;
        }
#pragma unroll
        for (int d = 0; d < 32; ++d) {
            const float* wr = w1 + (ch * 32 + d) * HID;
            float qd = q[d];
#pragma unroll
            for (int o = 0; o < HID; ++o) h[o] = fmaf(qd, wr[o], h[o]);
        }
    }
#pragma unroll
    for (int o = 0; o < HID; ++o) act[o * 64 + t] = fmaxf(h[o], 0.f);

    // layer 2
#pragma unroll
    for (int o = 0; o < HID; ++o) h[o] = b2[o];
    for (int j = 0; j < HID; ++j) {
        float hj = act[j * 64 + t];
        const float* wr = w2 + j * HID;
#pragma unroll
        for (int o = 0; o < HID; ++o) h[o] = fmaf(hj, wr[o], h[o]);
    }
#pragma unroll
    for (int o = 0; o < HID; ++o) act[o * 64 + t] = fmaxf(h[o], 0.f);

    // layer 3 -> recon (90 wide)
    float out[TA];
#pragma unroll
    for (int o = 0; o < TA; ++o) out[o] = b3[o];
    for (int j = 0; j < HID; ++j) {
        float hj = act[j * 64 + t];
        const float* wr = w3 + j * TA;
#pragma unroll
        for (int o = 0; o < TA; ++o) out[o] = fmaf(hj, wr[o], out[o]);
    }
    float* rr = recon_out + row * TA;
#pragma unroll
    for (int o = 0; o < TA; ++o) rr[o] = out[o];
}

// ---------------------------------------------------------------------------
// K3: finalize scalar loss
// ---------------------------------------------------------------------------
__global__ void k_loss(const float* __restrict__ acc, float* __restrict__ out) {
    out[0] = (acc[0] + acc[1] + acc[2] + acc[3]) * (1.0f / ((float)NSAMP * (float)DLAT));
}

extern "C" void kernel_launch(void* const* d_in, const int* in_sizes, int n_in,
                              void* d_out, int out_size, void* d_ws, size_t ws_size,
                              hipStream_t stream) {
    const float* state  = (const float*)d_in[0];
    const float* enc_w1 = (const float*)d_in[1];
    const float* enc_b1 = (const float*)d_in[2];
    const float* enc_w2 = (const float*)d_in[3];
    const float* enc_b2 = (const float*)d_in[4];
    const float* enc_w3 = (const float*)d_in[5];
    const float* enc_b3 = (const float*)d_in[6];
    const float* dec_w1 = (const float*)d_in[7];
    const float* dec_b1 = (const float*)d_in[8];
    const float* dec_w2 = (const float*)d_in[9];
    const float* dec_b2 = (const float*)d_in[10];
    const float* dec_w3 = (const float*)d_in[11];
    const float* dec_b3 = (const float*)d_in[12];
    const float* cb     = (const float*)d_in[13];

    float* out = (float*)d_out;
    float* loss_acc = (float*)d_ws;                 // 4 floats
    float* P = (float*)d_ws + 256;                  // 128x128 Gram table (64 KB)

    hipMemsetAsync(d_ws, 0, 16, stream);
    k_ptable<<<64, 256, 0, stream>>>(cb, P);
    k_encvq<<<NSAMP / 64, 64, 0, stream>>>(state, enc_w1, enc_b1, enc_w2, enc_b2,
                                           enc_w3, enc_b3, cb, P,
                                           out + OFF_CODE, loss_acc);
    k_dec<<<NSAMP / 64, 64, 0, stream>>>(out + OFF_CODE, cb,
                                         dec_w1, dec_b1, dec_w2, dec_b2, dec_w3, dec_b3,
                                         out, out + OFF_RECON);
    k_loss<<<1, 1, 0, stream>>>(loss_acc, out + OFF_LOSS);
}

// Round 2
// 1389.085 us; speedup vs baseline: 1.8284x; 1.8284x over previous
//
#include <hip/hip_runtime.h>
#include <hip/hip_bf16.h>

#define NSAMP 131072
#define TA    90
#define HID   128
#define DLAT  512
#define NC    128
#define SB    64      // samples per block

// d_out layout (float elements): quant[N*512], code[N*4], recon[N*90], loss[1]
#define OFF_CODE  67108864ll
#define OFF_RECON (67108864ll + 524288ll)
#define OFF_LOSS  (67108864ll + 524288ll + 11796480ll)

#define AST 68        // LDS stride for activation tiles (pad, 16B-aligned)
#define ZST 132       // LDS stride for zdot dump

// ---------------------------------------------------------------------------
// helpers
// ---------------------------------------------------------------------------
__device__ __forceinline__ void fma_tile(float (&acc)[8][4],
                                         const float* __restrict__ wl,
                                         const float* __restrict__ al) {
    float4 av = *(const float4*)al;
    float4 w0 = *(const float4*)wl;
    float4 w1 = *(const float4*)(wl + 4);
    float aa[4] = {av.x, av.y, av.z, av.w};
    float ww[8] = {w0.x, w0.y, w0.z, w0.w, w1.x, w1.y, w1.z, w1.w};
#pragma unroll
    for (int a = 0; a < 8; ++a)
#pragma unroll
        for (int b = 0; b < 4; ++b) acc[a][b] = fmaf(ww[a], aa[b], acc[a][b]);
}

// ---------------------------------------------------------------------------
// K0a: code-Gram table P[c1*128+c2] = e_c1 . e_c2   (into d_out quant region)
// ---------------------------------------------------------------------------
__global__ void k_ptable(const float* __restrict__ cb, float* __restrict__ P) {
    int gid = blockIdx.x * blockDim.x + threadIdx.x;   // 16384 threads
    int c1 = gid >> 7, c2 = gid & 127;
    const float4* a = (const float4*)(cb + c1 * DLAT);
    const float4* b = (const float4*)(cb + c2 * DLAT);
    float s = 0.f;
    for (int i = 0; i < DLAT / 4; ++i) {
        float4 x = a[i], y = b[i];
        s += x.x * y.x + x.y * y.y + x.z * y.z + x.w * y.w;
    }
    P[gid] = s;
}

// K0b: cbT[d*128+c] = cb[c*512+d]   (into d_out recon region, temp)
__global__ void k_cbt(const float* __restrict__ cb, float* __restrict__ cbT) {
    int gid = blockIdx.x * blockDim.x + threadIdx.x;   // 65536 threads
    int d = gid >> 7, c = gid & 127;
    cbT[gid] = cb[c * DLAT + d];
}

// ---------------------------------------------------------------------------
// K1: cooperative encoder + scoring + residual-VQ argmin.
// 64 samples/block, 256 threads, thread tile = 8 out x 4 samples.
// ---------------------------------------------------------------------------
__launch_bounds__(256, 2)
__global__ void k_encvq(const float* __restrict__ X,
                        const float* __restrict__ w1, const float* __restrict__ b1,
                        const float* __restrict__ w2, const float* __restrict__ b2,
                        const float* __restrict__ w3, const float* __restrict__ b3,
                        const float* __restrict__ cbT, const float* __restrict__ Pg,
                        float* __restrict__ codes_out, float* __restrict__ loss_acc) {
    __shared__ float Al[HID * AST];    // activations [j][s]
    __shared__ float Zl[HID * AST];    // z-chunk [d][s]
    __shared__ float Wl[16 * 128];     // weight chunk [j][o]
    const int t  = threadIdx.x;
    const int st = t & 15, ct = t >> 4;
    const int s0 = st * 4, o0 = ct * 8;
    const int row0 = blockIdx.x * SB;

    float rb1[8], rb2[8];
#pragma unroll
    for (int i = 0; i < 8; ++i) { rb1[i] = b1[o0 + i]; rb2[i] = b2[o0 + i]; }

    // stage X^T into Al
    for (int idx = t; idx < SB * TA; idx += 256) {
        int s = idx / TA, j = idx % TA;
        Al[j * AST + s] = X[(row0 + s) * TA + j];
    }
    __syncthreads();

    float acc[8][4];
    // ---- L1: 90 -> 128
#pragma unroll
    for (int a = 0; a < 8; ++a)
#pragma unroll
        for (int b = 0; b < 4; ++b) acc[a][b] = 0.f;
    for (int jb = 0; jb < TA; jb += 16) {
        int nj = min(16, TA - jb);
        __syncthreads();
        for (int idx = t; idx < nj * 128; idx += 256)
            Wl[idx] = w1[(jb + (idx >> 7)) * HID + (idx & 127)];
        __syncthreads();
        for (int j = 0; j < nj; ++j)
            fma_tile(acc, &Wl[j * 128 + o0], &Al[(jb + j) * AST + s0]);
    }
    __syncthreads();
#pragma unroll
    for (int a = 0; a < 8; ++a)
#pragma unroll
        for (int b = 0; b < 4; ++b)
            Al[(o0 + a) * AST + s0 + b] = fmaxf(acc[a][b] + rb1[a], 0.f);
    __syncthreads();

    // ---- L2: 128 -> 128
#pragma unroll
    for (int a = 0; a < 8; ++a)
#pragma unroll
        for (int b = 0; b < 4; ++b) acc[a][b] = 0.f;
    for (int jb = 0; jb < HID; jb += 16) {
        __syncthreads();
        for (int idx = t; idx < 16 * 128; idx += 256)
            Wl[idx] = w2[(jb + (idx >> 7)) * HID + (idx & 127)];
        __syncthreads();
#pragma unroll
        for (int j = 0; j < 16; ++j)
            fma_tile(acc, &Wl[j * 128 + o0], &Al[(jb + j) * AST + s0]);
    }
    __syncthreads();
#pragma unroll
    for (int a = 0; a < 8; ++a)
#pragma unroll
        for (int b = 0; b < 4; ++b)
            Al[(o0 + a) * AST + s0 + b] = fmaxf(acc[a][b] + rb2[a], 0.f);
    __syncthreads();

    // ---- L3 (128 -> 512, 4 chunks of 128) fused with scoring (z . cbT)
    float zacc[8][4];
#pragma unroll
    for (int a = 0; a < 8; ++a)
#pragma unroll
        for (int b = 0; b < 4; ++b) zacc[a][b] = 0.f;
    float znp = 0.f;

    for (int ch = 0; ch < 4; ++ch) {
#pragma unroll
        for (int a = 0; a < 8; ++a)
#pragma unroll
            for (int b = 0; b < 4; ++b) acc[a][b] = 0.f;
        for (int jb = 0; jb < HID; jb += 16) {
            __syncthreads();
            for (int idx = t; idx < 16 * 128; idx += 256)
                Wl[idx] = w3[(jb + (idx >> 7)) * DLAT + ch * 128 + (idx & 127)];
            __syncthreads();
#pragma unroll
            for (int j = 0; j < 16; ++j)
                fma_tile(acc, &Wl[j * 128 + o0], &Al[(jb + j) * AST + s0]);
        }
        float rb3[8];
#pragma unroll
        for (int i = 0; i < 8; ++i) rb3[i] = b3[ch * 128 + o0 + i];
        __syncthreads();   // prior scoring finished reading Zl
#pragma unroll
        for (int a = 0; a < 8; ++a)
#pragma unroll
            for (int b = 0; b < 4; ++b) {
                float v = acc[a][b] + rb3[a];
                znp = fmaf(v, v, znp);
                Zl[(o0 + a) * AST + s0 + b] = v;
            }
        __syncthreads();
        // scoring: zacc[c][s] += sum_d Zl[d][s] * cbT[d][c]
        for (int db = 0; db < 128; db += 16) {
            __syncthreads();
            for (int idx = t; idx < 16 * 128; idx += 256)
                Wl[idx] = cbT[(ch * 128 + db + (idx >> 7)) * 128 + (idx & 127)];
            __syncthreads();
#pragma unroll
            for (int j = 0; j < 16; ++j)
                fma_tile(zacc, &Wl[j * 128 + o0], &Zl[(db + j) * AST + s0]);
        }
    }

    // znorm block partial -> global (loss term)
    float zn = znp;
#pragma unroll
    for (int off = 32; off; off >>= 1) zn += __shfl_down(zn, off);
    if ((t & 63) == 0) atomicAdd(&loss_acc[0], zn);

    // dump zdot to LDS [s][c]
    __syncthreads();
#pragma unroll
    for (int a = 0; a < 8; ++a)
#pragma unroll
        for (int b = 0; b < 4; ++b)
            Al[(s0 + b) * ZST + o0 + a] = zacc[a][b];
    __syncthreads();

    // ---- per-sample residual-VQ argmin chain (wave 0, 1 sample/lane)
    if (t < SB) {
        float S1 = 0.f, Sp = 0.f, msum = 0.f;
        int cs[4];
#pragma unroll
        for (int g = 0; g < 4; ++g) {
            float best = 3.4e38f; int bi = g * 32;
            float bzd = 0.f, bnrm = 0.f, bacc = 0.f;
#pragma unroll
            for (int k = 0; k < 32; ++k) {
                int c = g * 32 + k;
                float zd = Al[t * ZST + c];
                float nr = Pg[c * NC + c];
                float a2 = 0.f;
#pragma unroll
                for (int gp = 0; gp < g; ++gp) a2 += Pg[cs[gp] * NC + c];
                float dist = nr - 2.f * (zd - a2);
                if (dist < best) { best = dist; bi = c; bzd = zd; bnrm = nr; bacc = a2; }
            }
            cs[g] = bi;
            S1 += bzd;
            Sp += bnrm + 2.f * bacc;
            msum += (Sp - 2.f * S1);
            codes_out[(row0 + t) * 4 + g] = (float)(bi - g * 32);
        }
#pragma unroll
        for (int off = 32; off; off >>= 1) msum += __shfl_down(msum, off);
        if (t == 0) atomicAdd(&loss_acc[1], msum);
    }
}

// ---------------------------------------------------------------------------
// K2: cooperative quant gather + decoder MLP.
// ---------------------------------------------------------------------------
__launch_bounds__(256, 3)
__global__ void k_dec(const float* __restrict__ codes_f, const float* __restrict__ cb,
                      const float* __restrict__ w1, const float* __restrict__ b1,
                      const float* __restrict__ w2, const float* __restrict__ b2,
                      const float* __restrict__ w3, const float* __restrict__ b3,
                      float* __restrict__ quant_out, float* __restrict__ recon_out) {
    __shared__ float Al[HID * AST];
    __shared__ float Wl[16 * 128];
    __shared__ int cods[SB * 4];
    const int t  = threadIdx.x;
    const int st = t & 15, ct = t >> 4;
    const int s0 = st * 4, o0 = ct * 8;
    const int row0 = blockIdx.x * SB;

    if (t < SB * 4) {
        int s = t >> 2, g = t & 3;
        cods[t] = (g << 5) + (int)codes_f[(row0 + s) * 4 + g];
    }
    float rb1[8], rb2[8];
#pragma unroll
    for (int i = 0; i < 8; ++i) { rb1[i] = b1[o0 + i]; rb2[i] = b2[o0 + i]; }
    __syncthreads();

    float acc[8][4];
#pragma unroll
    for (int a = 0; a < 8; ++a)
#pragma unroll
        for (int b = 0; b < 4; ++b) acc[a][b] = 0.f;

    // ---- L1: 512 -> 128, reduction in 4 chunks; build quant chunk + write out
    for (int dch = 0; dch < 4; ++dch) {
        __syncthreads();   // prior chunk GEMM done reading Al
        for (int idx = t; idx < SB * 128; idx += 256) {
            int s = idx >> 7, dd = idx & 127;
            int dg = (dch << 7) + dd;
            const int* cp = &cods[s * 4];
            float v = cb[cp[0] * DLAT + dg] + cb[cp[1] * DLAT + dg]
                    + cb[cp[2] * DLAT + dg] + cb[cp[3] * DLAT + dg];
            Al[dd * AST + s] = v;
            quant_out[(row0 + s) * DLAT + dg] = v;
        }
        __syncthreads();
        for (int jb = 0; jb < 128; jb += 16) {
            __syncthreads();
            for (int idx = t; idx < 16 * 128; idx += 256)
                Wl[idx] = w1[((dch << 7) + jb + (idx >> 7)) * HID + (idx & 127)];
            __syncthreads();
#pragma unroll
            for (int j = 0; j < 16; ++j)
                fma_tile(acc, &Wl[j * 128 + o0], &Al[(jb + j) * AST + s0]);
        }
    }
    __syncthreads();
#pragma unroll
    for (int a = 0; a < 8; ++a)
#pragma unroll
        for (int b = 0; b < 4; ++b)
            Al[(o0 + a) * AST + s0 + b] = fmaxf(acc[a][b] + rb1[a], 0.f);
    __syncthreads();

    // ---- L2: 128 -> 128
#pragma unroll
    for (int a = 0; a < 8; ++a)
#pragma unroll
        for (int b = 0; b < 4; ++b) acc[a][b] = 0.f;
    for (int jb = 0; jb < HID; jb += 16) {
        __syncthreads();
        for (int idx = t; idx < 16 * 128; idx += 256)
            Wl[idx] = w2[(jb + (idx >> 7)) * HID + (idx & 127)];
        __syncthreads();
#pragma unroll
        for (int j = 0; j < 16; ++j)
            fma_tile(acc, &Wl[j * 128 + o0], &Al[(jb + j) * AST + s0]);
    }
    __syncthreads();
#pragma unroll
    for (int a = 0; a < 8; ++a)
#pragma unroll
        for (int b = 0; b < 4; ++b)
            Al[(o0 + a) * AST + s0 + b] = fmaxf(acc[a][b] + rb2[a], 0.f);
    __syncthreads();

    // ---- L3: 128 -> 90 (Wl stride 96, zero-padded; threads ct>=12 duplicate)
    const int o0c = (o0 > 88) ? 88 : o0;
    float rb3[8];
#pragma unroll
    for (int i = 0; i < 8; ++i) rb3[i] = (o0 + i < TA) ? b3[o0 + i] : 0.f;
#pragma unroll
    for (int a = 0; a < 8; ++a)
#pragma unroll
        for (int b = 0; b < 4; ++b) acc[a][b] = 0.f;
    for (int jb = 0; jb < 128; jb += 16) {
        __syncthreads();
        for (int idx = t; idx < 16 * 96; idx += 256) {
            int j = idx / 96, o = idx - j * 96;
            Wl[j * 96 + o] = (o < TA) ? w3[(jb + j) * TA + o] : 0.f;
        }
        __syncthreads();
#pragma unroll
        for (int j = 0; j < 16; ++j)
            fma_tile(acc, &Wl[j * 96 + o0c], &Al[(jb + j) * AST + s0]);
    }
#pragma unroll
    for (int a = 0; a < 8; ++a)
        if (o0 + a < TA)
#pragma unroll
            for (int b = 0; b < 4; ++b)
                recon_out[(row0 + s0 + b) * TA + o0 + a] = acc[a][b] + rb3[a];
}

// ---------------------------------------------------------------------------
// K3: finalize scalar loss: sum_g mean = (4*znorm_tot + msum_tot) / (N*D)
// ---------------------------------------------------------------------------
__global__ void k_loss(const float* __restrict__ acc, float* __restrict__ out) {
    out[0] = (4.f * acc[0] + acc[1]) * (1.0f / ((float)NSAMP * (float)DLAT));
}

extern "C" void kernel_launch(void* const* d_in, const int* in_sizes, int n_in,
                              void* d_out, int out_size, void* d_ws, size_t ws_size,
                              hipStream_t stream) {
    const float* state  = (const float*)d_in[0];
    const float* enc_w1 = (const float*)d_in[1];
    const float* enc_b1 = (const float*)d_in[2];
    const float* enc_w2 = (const float*)d_in[3];
    const float* enc_b2 = (const float*)d_in[4];
    const float* enc_w3 = (const float*)d_in[5];
    const float* enc_b3 = (const float*)d_in[6];
    const float* dec_w1 = (const float*)d_in[7];
    const float* dec_b1 = (const float*)d_in[8];
    const float* dec_w2 = (const float*)d_in[9];
    const float* dec_b2 = (const float*)d_in[10];
    const float* dec_w3 = (const float*)d_in[11];
    const float* dec_b3 = (const float*)d_in[12];
    const float* cb     = (const float*)d_in[13];

    float* out = (float*)d_out;
    float* P   = out;               // temp in quant region (overwritten by k_dec)
    float* cbT = out + OFF_RECON;   // temp in recon region (overwritten by k_dec)
    float* loss_acc = (float*)d_ws;

    hipMemsetAsync(d_ws, 0, 16, stream);
    k_ptable<<<64, 256, 0, stream>>>(cb, P);
    k_cbt<<<256, 256, 0, stream>>>(cb, cbT);
    k_encvq<<<NSAMP / SB, 256, 0, stream>>>(state, enc_w1, enc_b1, enc_w2, enc_b2,
                                            enc_w3, enc_b3, cbT, P,
                                            out + OFF_CODE, loss_acc);
    k_dec<<<NSAMP / SB, 256, 0, stream>>>(out + OFF_CODE, cb,
                                          dec_w1, dec_b1, dec_w2, dec_b2,
                                          dec_w3, dec_b3,
                                          out, out + OFF_RECON);
    k_loss<<<1, 1, 0, stream>>>(loss_acc, out + OFF_LOSS);
}

// Round 3
// 552.057 us; speedup vs baseline: 4.6007x; 2.5162x over previous
//
#include <hip/hip_runtime.h>
#include <hip/hip_bf16.h>

#define NSAMP 131072
#define TA    90
#define HID   128
#define DLAT  512

// d_out layout (float elements): quant[N*512], code[N*4], recon[N*90], loss[1]
#define OFF_CODE  67108864ll
#define OFF_RECON (67108864ll + 524288ll)
#define OFF_LOSS  (67108864ll + 524288ll + 11796480ll)

// ---------------------------------------------------------------------------
// helpers
// ---------------------------------------------------------------------------
__device__ __forceinline__ float dot512(const float* __restrict__ a,
                                        const float* __restrict__ b) {
    float s = 0.f;
    for (int i = 0; i < 128; ++i) {
        float4 x = ((const float4*)a)[i], y = ((const float4*)b)[i];
        s += x.x * y.x + x.y * y.y + x.z * y.z + x.w * y.w;
    }
    return s;
}

__device__ __forceinline__ void fma_tile(float (&acc)[8][4],
                                         const float* __restrict__ wl,
                                         const float* __restrict__ al) {
    float4 av = *(const float4*)al;
    float4 w0 = *(const float4*)wl;
    float4 w1 = *(const float4*)(wl + 4);
    float aa[4] = {av.x, av.y, av.z, av.w};
    float ww[8] = {w0.x, w0.y, w0.z, w0.w, w1.x, w1.y, w1.z, w1.w};
#pragma unroll
    for (int a = 0; a < 8; ++a)
#pragma unroll
        for (int b = 0; b < 4; ++b) acc[a][b] = fmaf(ww[a], aa[b], acc[a][b]);
}

// Double-buffered 128-col-out GEMM chunk engine. Weight loads for chunk k+1
// issue before chunk k's compute (latency hidden); ds_write after barrier.
// Rows >= inRows are clamped (safe addr); the matching Act rows are ZERO so
// the garbage weights contribute nothing.
__device__ __forceinline__ void gemm_dbuf(const float* __restrict__ w, int wstride,
                                          int inRows, int nch,
                                          const float* __restrict__ Act,
                                          float* __restrict__ Wl,
                                          float (&acc)[8][4],
                                          int t, int o0, int s0) {
    const int wr = t >> 4;
    const int wc = (t & 15) * 8;
    float4 c0, c1;
    {
        int r = wr < inRows ? wr : inRows - 1;
        const float* p = w + (size_t)r * wstride + wc;
        c0 = *(const float4*)p; c1 = *(const float4*)(p + 4);
    }
    *(float4*)&Wl[wr * 128 + wc] = c0;
    *(float4*)&Wl[wr * 128 + wc + 4] = c1;
    __syncthreads();
    for (int ch = 0; ch < nch; ++ch) {
        const float* Wc = &Wl[(ch & 1) * 2048];
        const bool more = (ch + 1 < nch);
        if (more) {
            int rr = (ch + 1) * 16 + wr;
            int r = rr < inRows ? rr : inRows - 1;
            const float* p = w + (size_t)r * wstride + wc;
            c0 = *(const float4*)p; c1 = *(const float4*)(p + 4);
        }
        const float* Ab = Act + (ch * 16) * 64 + s0;
#pragma unroll
        for (int j = 0; j < 16; ++j)
            fma_tile(acc, &Wc[j * 128 + o0], Ab + j * 64);
        __syncthreads();
        if (more) {
            float* Wn = &Wl[((ch + 1) & 1) * 2048];
            *(float4*)&Wn[wr * 128 + wc] = c0;
            *(float4*)&Wn[wr * 128 + wc + 4] = c1;
            __syncthreads();
        }
    }
}

// ---------------------------------------------------------------------------
// K0: precompute tables.
//  tbl0: P[c1][c2]=e_c1.e_c2 ; t0[c]=cb_c.b3 ; csc=b3.b3
//  tbl1: M[j][c] = w3[j,:].cb[c,:]      (scoring operator)
//  tbl2: Q[i][j] = w3[i,:].w3[j,:] ; v[j]=w3[j,:].b3   (znorm quadratic form)
//  tbl3: cbW[c][o] = sum_d cb[c,d]*dec_w1[d,o]         (decoder L1 operator)
// ---------------------------------------------------------------------------
__global__ void k_prep(const float* __restrict__ cb, const float* __restrict__ w3,
                       const float* __restrict__ b3, const float* __restrict__ w1d,
                       float* __restrict__ P, float* __restrict__ M,
                       float* __restrict__ Q, float* __restrict__ t0,
                       float* __restrict__ v, float* __restrict__ csc,
                       float* __restrict__ cbW) {
    int tbl = blockIdx.x >> 6;
    int gid = (blockIdx.x & 63) * 256 + threadIdx.x;   // 0..16383
    int i = gid >> 7, j = gid & 127;
    if (tbl == 0) {
        P[gid] = dot512(cb + (size_t)i * 512, cb + (size_t)j * 512);
        if (gid < 128) t0[gid] = dot512(cb + (size_t)gid * 512, b3);
        if (gid == 0) csc[0] = dot512(b3, b3);
    } else if (tbl == 1) {
        M[gid] = dot512(w3 + (size_t)i * 512, cb + (size_t)j * 512);
    } else if (tbl == 2) {
        Q[gid] = dot512(w3 + (size_t)i * 512, w3 + (size_t)j * 512);
        if (gid < 128) v[gid] = dot512(w3 + (size_t)gid * 512, b3);
    } else {
        float s = 0.f;
        for (int d = 0; d < 512; ++d) s = fmaf(cb[(size_t)i * 512 + d], w1d[d * 128 + j], s);
        cbW[gid] = s;
    }
}

// ---------------------------------------------------------------------------
// K1: encoder (L1,L2) + scoring GEMM (M) + znorm GEMM (Q) + residual-VQ argmin.
// 64 samples/block, 256 threads, 8x4 register tiles. LDS 48 KB -> 3 blocks/CU.
// ---------------------------------------------------------------------------
__launch_bounds__(256, 3)
__global__ void k_encvq(const float* __restrict__ X,
                        const float* __restrict__ w1, const float* __restrict__ b1,
                        const float* __restrict__ w2, const float* __restrict__ b2,
                        const float* __restrict__ Mt, const float* __restrict__ Qt,
                        const float* __restrict__ t0g, const float* __restrict__ vg,
                        const float* __restrict__ cg, const float* __restrict__ Pg,
                        float* __restrict__ codes_out, float* __restrict__ loss_acc) {
    __shared__ __align__(16) float SH[12288];   // [Act 8192][Wl 4096]
    float* Act = SH;
    float* Wl  = SH + 8192;
    const int t = threadIdx.x;
    const int st = t & 15, ct = t >> 4;
    const int s0 = st * 4, o0 = ct * 8;
    const int row0 = blockIdx.x * 64;

    float rb1[8], rb2[8], rt0[8], rv[8];
#pragma unroll
    for (int i = 0; i < 8; ++i) {
        rb1[i] = b1[o0 + i]; rb2[i] = b2[o0 + i];
        rt0[i] = t0g[o0 + i]; rv[i] = vg[o0 + i];
    }

    // stage X^T (rows 90..95 zero-padded)
    for (int idx = t; idx < 96 * 64; idx += 256) {
        int j = idx >> 6, s = idx & 63;
        Act[idx] = (j < 90) ? X[(size_t)(row0 + s) * TA + j] : 0.f;
    }
    // (visibility via gemm prologue barrier)

    float acc[8][4];
#pragma unroll
    for (int a = 0; a < 8; ++a)
#pragma unroll
        for (int b = 0; b < 4; ++b) acc[a][b] = 0.f;
    gemm_dbuf(w1, HID, 90, 6, Act, Wl, acc, t, o0, s0);
#pragma unroll
    for (int a = 0; a < 8; ++a)
#pragma unroll
        for (int b = 0; b < 4; ++b)
            Act[(o0 + a) * 64 + s0 + b] = fmaxf(acc[a][b] + rb1[a], 0.f);

#pragma unroll
    for (int a = 0; a < 8; ++a)
#pragma unroll
        for (int b = 0; b < 4; ++b) acc[a][b] = 0.f;
    gemm_dbuf(w2, HID, 128, 8, Act, Wl, acc, t, o0, s0);
#pragma unroll
    for (int a = 0; a < 8; ++a)
#pragma unroll
        for (int b = 0; b < 4; ++b)
            Act[(o0 + a) * 64 + s0 + b] = fmaxf(acc[a][b] + rb2[a], 0.f);   // h2 in place

    float accS[8][4], accU[8][4];
#pragma unroll
    for (int a = 0; a < 8; ++a)
#pragma unroll
        for (int b = 0; b < 4; ++b) { accS[a][b] = 0.f; accU[a][b] = 0.f; }
    gemm_dbuf(Mt, 128, 128, 8, Act, Wl, accS, t, o0, s0);   // zdot partial
    gemm_dbuf(Qt, 128, 128, 8, Act, Wl, accU, t, o0, s0);   // Q*h

    // znorm partials: sum_a (U + 2v)*h2  -> PZ[ct][s] at SH+8320 (Wl dead)
#pragma unroll
    for (int b = 0; b < 4; ++b) {
        float p = 0.f;
#pragma unroll
        for (int a = 0; a < 8; ++a)
            p = fmaf(accU[a][b] + 2.f * rv[a], Act[(o0 + a) * 64 + s0 + b], p);
        SH[8320 + ct * 64 + s0 + b] = p;
    }
    __syncthreads();
    // dump zdot (+t0) over Act, stride 129 (bank-spread)
#pragma unroll
    for (int a = 0; a < 8; ++a)
#pragma unroll
        for (int b = 0; b < 4; ++b)
            SH[(s0 + b) * 129 + (o0 + a)] = accS[a][b] + rt0[a];
    __syncthreads();

    if (t < 64) {
        float znorm = cg[0];
#pragma unroll
        for (int q = 0; q < 16; ++q) znorm += SH[8320 + q * 64 + t];
        float S1 = 0.f, Sp = 0.f, msum = 0.f;
        int cs[4];
#pragma unroll
        for (int g = 0; g < 4; ++g) {
            float best = 3.4e38f; int bi = g * 32;
            float bzd = 0.f, bnrm = 0.f, bacc = 0.f;
#pragma unroll
            for (int k = 0; k < 32; ++k) {
                int c = g * 32 + k;
                float zd = SH[t * 129 + c];
                float nr = Pg[c * 128 + c];
                float a2 = 0.f;
#pragma unroll
                for (int gp = 0; gp < g; ++gp) a2 += Pg[cs[gp] * 128 + c];
                float dist = nr - 2.f * (zd - a2);
                if (dist < best) { best = dist; bi = c; bzd = zd; bnrm = nr; bacc = a2; }
            }
            cs[g] = bi;
            S1 += bzd;
            Sp += bnrm + 2.f * bacc;
            msum += (znorm - 2.f * S1 + Sp);     // ||r_after_g||^2
            codes_out[(size_t)(row0 + t) * 4 + g] = (float)(bi - g * 32);
        }
#pragma unroll
        for (int off = 32; off; off >>= 1) msum += __shfl_down(msum, off);
        if (t == 0) atomicAdd(&loss_acc[0], msum);
    }
}

// ---------------------------------------------------------------------------
// K2: quant write + decoder via cbW gather (L1) + GEMM L2 + GEMM L3(90).
// ---------------------------------------------------------------------------
__launch_bounds__(256, 3)
__global__ void k_dec(const float* __restrict__ codes_f, const float* __restrict__ cb,
                      const float* __restrict__ cbW,
                      const float* __restrict__ b1, const float* __restrict__ w2,
                      const float* __restrict__ b2, const float* __restrict__ w3,
                      const float* __restrict__ b3,
                      float* __restrict__ quant_out, float* __restrict__ recon_out) {
    __shared__ __align__(16) float SH[12288];
    __shared__ int cods[256];
    float* Act = SH;
    float* Wl  = SH + 8192;
    const int t = threadIdx.x;
    const int st = t & 15, ct = t >> 4;
    const int s0 = st * 4, o0 = ct * 8;
    const int row0 = blockIdx.x * 64;

    cods[t] = ((t & 3) << 5) + (int)codes_f[(size_t)row0 * 4 + t];
    float rb1[8], rb2[8];
#pragma unroll
    for (int i = 0; i < 8; ++i) { rb1[i] = b1[o0 + i]; rb2[i] = b2[o0 + i]; }
    __syncthreads();

    // quant = sum of 4 codebook rows; streaming write
    for (int i = 0; i < 32; ++i) {
        int idx4 = i * 256 + t;            // float4 index in [64][128]
        int s = idx4 >> 7, d4 = (idx4 & 127) * 4;
        const int* cp = &cods[s * 4];
        float4 a = *(const float4*)&cb[(size_t)cp[0] * 512 + d4];
        float4 b = *(const float4*)&cb[(size_t)cp[1] * 512 + d4];
        float4 c = *(const float4*)&cb[(size_t)cp[2] * 512 + d4];
        float4 d = *(const float4*)&cb[(size_t)cp[3] * 512 + d4];
        float4 vv;
        vv.x = a.x + b.x + c.x + d.x;
        vv.y = a.y + b.y + c.y + d.y;
        vv.z = a.z + b.z + c.z + d.z;
        vv.w = a.w + b.w + c.w + d.w;
        *(float4*)&quant_out[(size_t)(row0 + s) * 512 + d4] = vv;
    }

    // L1 via cbW gather: h1[o][s] = relu(sum_g cbW[c_g][o] + b1[o])
    float acc[8][4];
#pragma unroll
    for (int b = 0; b < 4; ++b) {
        const int* cp = &cods[(s0 + b) * 4];
        float u[8] = {0, 0, 0, 0, 0, 0, 0, 0};
#pragma unroll
        for (int g = 0; g < 4; ++g) {
            const float* r = &cbW[(size_t)cp[g] * 128 + o0];
            float4 x0 = *(const float4*)r, x1 = *(const float4*)(r + 4);
            u[0] += x0.x; u[1] += x0.y; u[2] += x0.z; u[3] += x0.w;
            u[4] += x1.x; u[5] += x1.y; u[6] += x1.z; u[7] += x1.w;
        }
#pragma unroll
        for (int a = 0; a < 8; ++a) acc[a][b] = u[a];
    }
#pragma unroll
    for (int a = 0; a < 8; ++a)
#pragma unroll
        for (int b = 0; b < 4; ++b)
            Act[(o0 + a) * 64 + s0 + b] = fmaxf(acc[a][b] + rb1[a], 0.f);

    // L2 GEMM
#pragma unroll
    for (int a = 0; a < 8; ++a)
#pragma unroll
        for (int b = 0; b < 4; ++b) acc[a][b] = 0.f;
    gemm_dbuf(w2, HID, 128, 8, Act, Wl, acc, t, o0, s0);
#pragma unroll
    for (int a = 0; a < 8; ++a)
#pragma unroll
        for (int b = 0; b < 4; ++b)
            Act[(o0 + a) * 64 + s0 + b] = fmaxf(acc[a][b] + rb2[a], 0.f);

    // L3 GEMM: weights [128][90], Wl stride 96 (cols 90..95 garbage, discarded)
    const int o0c = (o0 > 88) ? 88 : o0;
    float accO[8][4];
#pragma unroll
    for (int a = 0; a < 8; ++a)
#pragma unroll
        for (int b = 0; b < 4; ++b) accO[a][b] = 0.f;
    float n[6];
#pragma unroll
    for (int i = 0; i < 6; ++i) {
        int idx = t + i * 256;
        int r = idx / 96, c2 = idx - r * 96;
        int cc = c2 < 90 ? c2 : 89;
        n[i] = w3[(size_t)r * TA + cc];
    }
#pragma unroll
    for (int i = 0; i < 6; ++i) Wl[t + i * 256] = n[i];
    __syncthreads();
    for (int ch = 0; ch < 8; ++ch) {
        const float* Wc = &Wl[(ch & 1) * 2048];
        const bool more = (ch + 1 < 8);
        if (more) {
#pragma unroll
            for (int i = 0; i < 6; ++i) {
                int idx = t + i * 256;
                int r = idx / 96, c2 = idx - r * 96;
                int cc = c2 < 90 ? c2 : 89;
                n[i] = w3[(size_t)((ch + 1) * 16 + r) * TA + cc];
            }
        }
        const float* Ab = Act + (ch * 16) * 64 + s0;
#pragma unroll
        for (int j = 0; j < 16; ++j)
            fma_tile(accO, &Wc[j * 96 + o0c], Ab + j * 64);
        __syncthreads();
        if (more) {
            float* Wn = &Wl[((ch + 1) & 1) * 2048];
#pragma unroll
            for (int i = 0; i < 6; ++i) Wn[t + i * 256] = n[i];
            __syncthreads();
        }
    }
    float rb3[8];
#pragma unroll
    for (int i = 0; i < 8; ++i) rb3[i] = (o0 + i < TA) ? b3[o0 + i] : 0.f;
#pragma unroll
    for (int a = 0; a < 8; ++a)
        if (o0 + a < TA)
#pragma unroll
            for (int b = 0; b < 4; ++b)
                recon_out[(size_t)(row0 + s0 + b) * TA + o0 + a] = accO[a][b] + rb3[a];
}

// ---------------------------------------------------------------------------
__global__ void k_loss(const float* __restrict__ acc, float* __restrict__ out) {
    out[0] = acc[0] * (1.0f / ((float)NSAMP * (float)DLAT));
}

extern "C" void kernel_launch(void* const* d_in, const int* in_sizes, int n_in,
                              void* d_out, int out_size, void* d_ws, size_t ws_size,
                              hipStream_t stream) {
    const float* state  = (const float*)d_in[0];
    const float* enc_w1 = (const float*)d_in[1];
    const float* enc_b1 = (const float*)d_in[2];
    const float* enc_w2 = (const float*)d_in[3];
    const float* enc_b2 = (const float*)d_in[4];
    const float* enc_w3 = (const float*)d_in[5];
    const float* enc_b3 = (const float*)d_in[6];
    const float* dec_w1 = (const float*)d_in[7];
    const float* dec_b1 = (const float*)d_in[8];
    const float* dec_w2 = (const float*)d_in[9];
    const float* dec_b2 = (const float*)d_in[10];
    const float* dec_w3 = (const float*)d_in[11];
    const float* dec_b3 = (const float*)d_in[12];
    const float* cb     = (const float*)d_in[13];

    float* out = (float*)d_out;
    // temp tables parked in the quant region (k_dec overwrites later):
    float* P   = out;
    float* M   = out + 16384;
    float* Q   = out + 32768;
    float* t0  = out + 49152;
    float* v   = out + 49280;
    float* csc = out + 49408;
    float* loss_acc = (float*)d_ws;
    float* cbW = (float*)d_ws + 256;          // 64 KB (R1-proven ws footprint)

    hipMemsetAsync(d_ws, 0, 16, stream);
    k_prep<<<256, 256, 0, stream>>>(cb, enc_w3, enc_b3, dec_w1,
                                    P, M, Q, t0, v, csc, cbW);
    k_encvq<<<NSAMP / 64, 256, 0, stream>>>(state, enc_w1, enc_b1, enc_w2, enc_b2,
                                            M, Q, t0, v, csc, P,
                                            out + OFF_CODE, loss_acc);
    k_dec<<<NSAMP / 64, 256, 0, stream>>>(out + OFF_CODE, cb, cbW,
                                          dec_b1, dec_w2, dec_b2, dec_w3, dec_b3,
                                          out, out + OFF_RECON);
    k_loss<<<1, 1, 0, stream>>>(loss_acc, out + OFF_LOSS);
}

// Round 4
// 400.731 us; speedup vs baseline: 6.3380x; 1.3776x over previous
//
#include <hip/hip_runtime.h>
#include <hip/hip_bf16.h>

#define NSAMP 131072
#define TA    90
#define HID   128
#define DLAT  512

// d_out layout (float elements): quant[N*512], code[N*4], recon[N*90], loss[1]
#define OFF_CODE  67108864ll
#define OFF_RECON (67108864ll + 524288ll)
#define OFF_LOSS  (67108864ll + 524288ll + 11796480ll)

typedef __attribute__((ext_vector_type(8))) short bf16x8;
typedef __attribute__((ext_vector_type(4))) short s16x4;
typedef __attribute__((ext_vector_type(4))) float f32x4;
typedef unsigned short ushort_t;
#define MFMA16(a, b, c) __builtin_amdgcn_mfma_f32_16x16x32_bf16(a, b, c, 0, 0, 0)

__device__ __forceinline__ ushort_t f2bf(float f) {
    unsigned u = __float_as_uint(f);
    u = (u + 0x7FFF + ((u >> 16) & 1)) >> 16;     // RNE
    return (ushort_t)u;
}

__device__ __forceinline__ float dot512(const float* __restrict__ a,
                                        const float* __restrict__ b) {
    float s = 0.f;
    for (int i = 0; i < 128; ++i) {
        float4 x = ((const float4*)a)[i], y = ((const float4*)b)[i];
        s += x.x * y.x + x.y * y.y + x.z * y.z + x.w * y.w;
    }
    return s;
}

__device__ __forceinline__ void fma_tile(float (&acc)[8][4],
                                         const float* __restrict__ wl,
                                         const float* __restrict__ al) {
    float4 av = *(const float4*)al;
    float4 w0 = *(const float4*)wl;
    float4 w1 = *(const float4*)(wl + 4);
    float aa[4] = {av.x, av.y, av.z, av.w};
    float ww[8] = {w0.x, w0.y, w0.z, w0.w, w1.x, w1.y, w1.z, w1.w};
#pragma unroll
    for (int a = 0; a < 8; ++a)
#pragma unroll
        for (int b = 0; b < 4; ++b) acc[a][b] = fmaf(ww[a], aa[b], acc[a][b]);
}

// Double-buffered fp32 GEMM chunk engine (unchanged from R3 — argmin-exact).
__device__ __forceinline__ void gemm_dbuf(const float* __restrict__ w, int wstride,
                                          int inRows, int nch,
                                          const float* __restrict__ Act,
                                          float* __restrict__ Wl,
                                          float (&acc)[8][4],
                                          int t, int o0, int s0) {
    const int wr = t >> 4;
    const int wc = (t & 15) * 8;
    float4 c0, c1;
    {
        int r = wr < inRows ? wr : inRows - 1;
        const float* p = w + (size_t)r * wstride + wc;
        c0 = *(const float4*)p; c1 = *(const float4*)(p + 4);
    }
    *(float4*)&Wl[wr * 128 + wc] = c0;
    *(float4*)&Wl[wr * 128 + wc + 4] = c1;
    __syncthreads();
    for (int ch = 0; ch < nch; ++ch) {
        const float* Wc = &Wl[(ch & 1) * 2048];
        const bool more = (ch + 1 < nch);
        if (more) {
            int rr = (ch + 1) * 16 + wr;
            int r = rr < inRows ? rr : inRows - 1;
            const float* p = w + (size_t)r * wstride + wc;
            c0 = *(const float4*)p; c1 = *(const float4*)(p + 4);
        }
        const float* Ab = Act + (ch * 16) * 64 + s0;
#pragma unroll
        for (int j = 0; j < 16; ++j)
            fma_tile(acc, &Wc[j * 128 + o0], Ab + j * 64);
        __syncthreads();
        if (more) {
            float* Wn = &Wl[((ch + 1) & 1) * 2048];
            *(float4*)&Wn[wr * 128 + wc] = c0;
            *(float4*)&Wn[wr * 128 + wc + 4] = c1;
            __syncthreads();
        }
    }
}

// ---------------------------------------------------------------------------
// K0: precompute tables (fp32: P, M, t0, v, csc, cbW; bf16: Qbf, w2dT, w3dT).
// ---------------------------------------------------------------------------
__global__ void k_prep(const float* __restrict__ cb, const float* __restrict__ w3,
                       const float* __restrict__ b3, const float* __restrict__ w1d,
                       const float* __restrict__ w2d, const float* __restrict__ w3d,
                       float* __restrict__ P, float* __restrict__ M,
                       float* __restrict__ t0, float* __restrict__ v,
                       float* __restrict__ csc, float* __restrict__ cbW,
                       ushort_t* __restrict__ Qbf, ushort_t* __restrict__ w2bf,
                       ushort_t* __restrict__ w3bf) {
    int tbl = blockIdx.x >> 6;
    int gid = (blockIdx.x & 63) * 256 + threadIdx.x;   // 0..16383
    int i = gid >> 7, j = gid & 127;
    if (tbl == 0) {
        P[gid] = dot512(cb + (size_t)i * 512, cb + (size_t)j * 512);
        if (gid < 128) t0[gid] = dot512(cb + (size_t)gid * 512, b3);
        if (gid == 0) csc[0] = dot512(b3, b3);
    } else if (tbl == 1) {
        M[gid] = dot512(w3 + (size_t)i * 512, cb + (size_t)j * 512);
    } else if (tbl == 2) {
        Qbf[gid] = f2bf(dot512(w3 + (size_t)i * 512, w3 + (size_t)j * 512));
        if (gid < 128) v[gid] = dot512(w3 + (size_t)gid * 512, b3);
    } else if (tbl == 3) {
        float s = 0.f;
        for (int d = 0; d < 512; ++d) s = fmaf(cb[(size_t)i * 512 + d], w1d[d * 128 + j], s);
        cbW[gid] = s;
    } else if (tbl == 4) {
        w2bf[gid] = f2bf(w2d[j * 128 + i]);            // [o][j] = w2[j][o]
    } else {
        if (gid < 96 * 128)
            w3bf[gid] = (i < 90) ? f2bf(w3d[j * TA + i]) : (ushort_t)0;
    }
}

// ---------------------------------------------------------------------------
// K1: encoder (L1,L2 fp32) + Q-MFMA (znorm, bf16 — loss only) + M-GEMM (fp32)
//     + residual-VQ argmin. LDS 53 KB -> 3 blocks/CU.
// ---------------------------------------------------------------------------
__launch_bounds__(256, 3)
__global__ void k_encvq(const float* __restrict__ X,
                        const float* __restrict__ w1, const float* __restrict__ b1,
                        const float* __restrict__ w2, const float* __restrict__ b2,
                        const float* __restrict__ Mt, const ushort_t* __restrict__ Qbf,
                        const float* __restrict__ t0g, const float* __restrict__ vg,
                        const float* __restrict__ cg, const float* __restrict__ Pg,
                        float* __restrict__ codes_out, float* __restrict__ loss_acc) {
    __shared__ __align__(16) float SH[13312];   // [Act 8192][Wl 4096][PZ 1024]
    float* Act = SH;
    float* Wl  = SH + 8192;
    const int t = threadIdx.x;
    const int st = t & 15, ct = t >> 4;
    const int s0 = st * 4, o0 = ct * 8;
    const int row0 = blockIdx.x * 64;

    float rb1[8], rb2[8], rt0[8];
#pragma unroll
    for (int i = 0; i < 8; ++i) {
        rb1[i] = b1[o0 + i]; rb2[i] = b2[o0 + i]; rt0[i] = t0g[o0 + i];
    }

    // stage X^T (rows 90..95 zero-padded)
    for (int idx = t; idx < 96 * 64; idx += 256) {
        int j = idx >> 6, s = idx & 63;
        Act[idx] = (j < 90) ? X[(size_t)(row0 + s) * TA + j] : 0.f;
    }

    float acc[8][4];
#pragma unroll
    for (int a = 0; a < 8; ++a)
#pragma unroll
        for (int b = 0; b < 4; ++b) acc[a][b] = 0.f;
    gemm_dbuf(w1, HID, 90, 6, Act, Wl, acc, t, o0, s0);
#pragma unroll
    for (int a = 0; a < 8; ++a)
#pragma unroll
        for (int b = 0; b < 4; ++b)
            Act[(o0 + a) * 64 + s0 + b] = fmaxf(acc[a][b] + rb1[a], 0.f);

#pragma unroll
    for (int a = 0; a < 8; ++a)
#pragma unroll
        for (int b = 0; b < 4; ++b) acc[a][b] = 0.f;
    gemm_dbuf(w2, HID, 128, 8, Act, Wl, acc, t, o0, s0);

    // L2 epilogue: h2 -> Act (fp32, argmin path) + h2bf -> Wl region (bf16 swz)
    {
        ushort_t* h2w = (ushort_t*)Wl;
#pragma unroll
        for (int b = 0; b < 4; ++b) {
            int s = s0 + b;
            bf16x8 pk;
#pragma unroll
            for (int a = 0; a < 8; ++a) {
                float hv = fmaxf(acc[a][b] + rb2[a], 0.f);
                Act[(o0 + a) * 64 + s] = hv;
                pk[a] = (short)f2bf(hv);
            }
            *(bf16x8*)&h2w[((s << 7) + o0) ^ ((s & 7) << 3)] = pk;
        }
    }
    __syncthreads();

    // ---- Q-phase: U = Q*h2 via bf16 MFMA; znorm partials -> PZ (loss only)
    {
        const int wv = t >> 6, lane = t & 63, lr = lane & 15, lg = lane >> 4;
        const ushort_t* h2bf = (const ushort_t*)Wl;
        f32x4 qc[2][4];
#pragma unroll
        for (int m = 0; m < 2; ++m)
#pragma unroll
            for (int n = 0; n < 4; ++n) qc[m][n] = (f32x4){0.f, 0.f, 0.f, 0.f};
#pragma unroll
        for (int kt = 0; kt < 4; ++kt) {
            bf16x8 af[2], bfr[4];
#pragma unroll
            for (int m = 0; m < 2; ++m)
                af[m] = *(const bf16x8*)&Qbf[(32 * wv + 16 * m + lr) * 128 + kt * 32 + lg * 8];
#pragma unroll
            for (int n = 0; n < 4; ++n) {
                int s = 16 * n + lr;
                bfr[n] = *(const bf16x8*)&h2bf[((s << 7) + kt * 32 + lg * 8) ^ ((s & 7) << 3)];
            }
#pragma unroll
            for (int m = 0; m < 2; ++m)
#pragma unroll
                for (int n = 0; n < 4; ++n)
                    qc[m][n] = MFMA16(af[m], bfr[n], qc[m][n]);
        }
        float v2[2][4];
#pragma unroll
        for (int m = 0; m < 2; ++m)
#pragma unroll
            for (int r = 0; r < 4; ++r) v2[m][r] = 2.f * vg[32 * wv + 16 * m + lg * 4 + r];
#pragma unroll
        for (int n = 0; n < 4; ++n) {
            int s = 16 * n + lr;
            float p = 0.f;
#pragma unroll
            for (int m = 0; m < 2; ++m)
#pragma unroll
                for (int r = 0; r < 4; ++r) {
                    int o = 32 * wv + 16 * m + lg * 4 + r;
                    p = fmaf(qc[m][n][r] + v2[m][r], Act[o * 64 + s], p);
                }
            SH[12288 + (wv * 4 + lg) * 64 + s] = p;
        }
    }
    __syncthreads();   // h2bf reads done before M staging reuses Wl

    // ---- M-scoring GEMM (fp32 — argmin-critical)
    float accS[8][4];
#pragma unroll
    for (int a = 0; a < 8; ++a)
#pragma unroll
        for (int b = 0; b < 4; ++b) accS[a][b] = 0.f;
    gemm_dbuf(Mt, 128, 128, 8, Act, Wl, accS, t, o0, s0);

    // dump zdot (+t0) over Act, stride 129
#pragma unroll
    for (int a = 0; a < 8; ++a)
#pragma unroll
        for (int b = 0; b < 4; ++b)
            SH[(s0 + b) * 129 + (o0 + a)] = accS[a][b] + rt0[a];
    __syncthreads();

    if (t < 64) {
        float znorm = cg[0];
#pragma unroll
        for (int q = 0; q < 16; ++q) znorm += SH[12288 + q * 64 + t];
        float S1 = 0.f, Sp = 0.f, msum = 0.f;
        int cs[4];
#pragma unroll
        for (int g = 0; g < 4; ++g) {
            float best = 3.4e38f; int bi = g * 32;
            float bzd = 0.f, bnrm = 0.f, bacc = 0.f;
#pragma unroll
            for (int k = 0; k < 32; ++k) {
                int c = g * 32 + k;
                float zd = SH[t * 129 + c];
                float nr = Pg[c * 128 + c];
                float a2 = 0.f;
#pragma unroll
                for (int gp = 0; gp < g; ++gp) a2 += Pg[cs[gp] * 128 + c];
                float dist = nr - 2.f * (zd - a2);
                if (dist < best) { best = dist; bi = c; bzd = zd; bnrm = nr; bacc = a2; }
            }
            cs[g] = bi;
            S1 += bzd;
            Sp += bnrm + 2.f * bacc;
            msum += (znorm - 2.f * S1 + Sp);
            codes_out[(size_t)(row0 + t) * 4 + g] = (float)(bi - g * 32);
        }
#pragma unroll
        for (int off = 32; off; off >>= 1) msum += __shfl_down(msum, off);
        if (t == 0) atomicAdd(&loss_acc[0], msum);
    }
}

// ---------------------------------------------------------------------------
// K2: quant write (fp32) + cbW-gather L1 (fp32) + bf16-MFMA decoder L2/L3.
// LDS 39.4 KB -> 4 blocks/CU.
// ---------------------------------------------------------------------------
__launch_bounds__(256, 4)
__global__ void k_dec(const float* __restrict__ codes_f, const float* __restrict__ cb,
                      const float* __restrict__ cbW, const float* __restrict__ b1,
                      const ushort_t* __restrict__ w2bf, const float* __restrict__ b2,
                      const ushort_t* __restrict__ w3bf, const float* __restrict__ b3,
                      float* __restrict__ quant_out, float* __restrict__ recon_out) {
    __shared__ __align__(16) unsigned char SHB[39424];
    int* cods = (int*)SHB;                         // dead before h2bf written
    ushort_t* h2bf = (ushort_t*)SHB;               // [64 s][128 j] swz, 16 KB
    ushort_t* h1bf = (ushort_t*)(SHB + 16384);     // [64 s][128 j] swz, 16 KB
    float* Rl = (float*)(SHB + 16384);             // flat [64*90], overlays h1bf
    const int t = threadIdx.x;
    const int st = t & 15, ct = t >> 4;
    const int s0 = st * 4, o0 = ct * 8;
    const int row0 = blockIdx.x * 64;

    cods[t] = ((t & 3) << 5) + (int)codes_f[(size_t)row0 * 4 + t];
    float rb1[8];
#pragma unroll
    for (int i = 0; i < 8; ++i) rb1[i] = b1[o0 + i];
    __syncthreads();

    // quant = sum of 4 codebook rows; streaming fp32 write (exact)
    for (int i = 0; i < 32; ++i) {
        int idx4 = i * 256 + t;
        int s = idx4 >> 7, d4 = (idx4 & 127) * 4;
        const int* cp = &cods[s * 4];
        float4 a = *(const float4*)&cb[(size_t)cp[0] * 512 + d4];
        float4 b = *(const float4*)&cb[(size_t)cp[1] * 512 + d4];
        float4 c = *(const float4*)&cb[(size_t)cp[2] * 512 + d4];
        float4 d = *(const float4*)&cb[(size_t)cp[3] * 512 + d4];
        float4 vv;
        vv.x = a.x + b.x + c.x + d.x;
        vv.y = a.y + b.y + c.y + d.y;
        vv.z = a.z + b.z + c.z + d.z;
        vv.w = a.w + b.w + c.w + d.w;
        *(float4*)&quant_out[(size_t)(row0 + s) * 512 + d4] = vv;
    }

    // L1 via cbW gather (fp32) -> h1bf (bf16, swizzled [s][j])
    {
        float accL[8][4];
#pragma unroll
        for (int b = 0; b < 4; ++b) {
            const int* cp = &cods[(s0 + b) * 4];
            float u[8] = {0, 0, 0, 0, 0, 0, 0, 0};
#pragma unroll
            for (int g = 0; g < 4; ++g) {
                const float* r = &cbW[(size_t)cp[g] * 128 + o0];
                float4 x0 = *(const float4*)r, x1 = *(const float4*)(r + 4);
                u[0] += x0.x; u[1] += x0.y; u[2] += x0.z; u[3] += x0.w;
                u[4] += x1.x; u[5] += x1.y; u[6] += x1.z; u[7] += x1.w;
            }
#pragma unroll
            for (int a = 0; a < 8; ++a) accL[a][b] = u[a];
        }
#pragma unroll
        for (int b = 0; b < 4; ++b) {
            int s = s0 + b;
            bf16x8 pk;
#pragma unroll
            for (int a = 0; a < 8; ++a)
                pk[a] = (short)f2bf(fmaxf(accL[a][b] + rb1[a], 0.f));
            *(bf16x8*)&h1bf[((s << 7) + o0) ^ ((s & 7) << 3)] = pk;
        }
    }
    __syncthreads();

    const int wv = t >> 6, lane = t & 63, lr = lane & 15, lg = lane >> 4;

    // ---- L2: h2 = relu(w2^T h1 + b2) via MFMA; wave wv owns rows [32wv,32wv+32)
    {
        f32x4 c2[2][4];
#pragma unroll
        for (int m = 0; m < 2; ++m)
#pragma unroll
            for (int n = 0; n < 4; ++n) c2[m][n] = (f32x4){0.f, 0.f, 0.f, 0.f};
#pragma unroll
        for (int kt = 0; kt < 4; ++kt) {
            bf16x8 af[2], bfr[4];
#pragma unroll
            for (int m = 0; m < 2; ++m)
                af[m] = *(const bf16x8*)&w2bf[(32 * wv + 16 * m + lr) * 128 + kt * 32 + lg * 8];
#pragma unroll
            for (int n = 0; n < 4; ++n) {
                int s = 16 * n + lr;
                bfr[n] = *(const bf16x8*)&h1bf[((s << 7) + kt * 32 + lg * 8) ^ ((s & 7) << 3)];
            }
#pragma unroll
            for (int m = 0; m < 2; ++m)
#pragma unroll
                for (int n = 0; n < 4; ++n)
                    c2[m][n] = MFMA16(af[m], bfr[n], c2[m][n]);
        }
        float rb[2][4];
#pragma unroll
        for (int m = 0; m < 2; ++m)
#pragma unroll
            for (int r = 0; r < 4; ++r) rb[m][r] = b2[32 * wv + 16 * m + lg * 4 + r];
#pragma unroll
        for (int m = 0; m < 2; ++m)
#pragma unroll
            for (int n = 0; n < 4; ++n) {
                int s = 16 * n + lr;
                s16x4 pk;
#pragma unroll
                for (int r = 0; r < 4; ++r)
                    pk[r] = (short)f2bf(fmaxf(c2[m][n][r] + rb[m][r], 0.f));
                int ob = 32 * wv + 16 * m + lg * 4;
                *(s16x4*)&h2bf[((s << 7) + ob) ^ ((s & 7) << 3)] = pk;
            }
    }
    __syncthreads();

    // ---- L3: recon = w3^T h2 + b3 via MFMA; wave wv owns sample tile wv
    {
        f32x4 c3[6];
#pragma unroll
        for (int m = 0; m < 6; ++m) c3[m] = (f32x4){0.f, 0.f, 0.f, 0.f};
        const int sB = 16 * wv + lr;
#pragma unroll
        for (int kt = 0; kt < 4; ++kt) {
            bf16x8 bfr = *(const bf16x8*)&h2bf[((sB << 7) + kt * 32 + lg * 8) ^ ((sB & 7) << 3)];
#pragma unroll
            for (int mt = 0; mt < 6; ++mt) {
                bf16x8 af = *(const bf16x8*)&w3bf[(16 * mt + lr) * 128 + kt * 32 + lg * 8];
                c3[mt] = MFMA16(af, bfr, c3[mt]);
            }
        }
#pragma unroll
        for (int mt = 0; mt < 6; ++mt)
#pragma unroll
            for (int r = 0; r < 4; ++r) {
                int o = 16 * mt + lg * 4 + r;
                if (o < 90) Rl[sB * 90 + o] = c3[mt][r] + b3[o];
            }
    }
    __syncthreads();

    // coalesced copy-out: 64*90 floats = 1440 float4
    {
        const float4* R4 = (const float4*)Rl;
        float4* G4 = (float4*)(recon_out + (size_t)row0 * 90);
#pragma unroll
        for (int it = 0; it < 6; ++it) {
            int i4 = it * 256 + t;
            if (i4 < 1440) G4[i4] = R4[i4];
        }
    }
}

// ---------------------------------------------------------------------------
__global__ void k_loss(const float* __restrict__ acc, float* __restrict__ out) {
    out[0] = acc[0] * (1.0f / ((float)NSAMP * (float)DLAT));
}

extern "C" void kernel_launch(void* const* d_in, const int* in_sizes, int n_in,
                              void* d_out, int out_size, void* d_ws, size_t ws_size,
                              hipStream_t stream) {
    const float* state  = (const float*)d_in[0];
    const float* enc_w1 = (const float*)d_in[1];
    const float* enc_b1 = (const float*)d_in[2];
    const float* enc_w2 = (const float*)d_in[3];
    const float* enc_b2 = (const float*)d_in[4];
    const float* enc_w3 = (const float*)d_in[5];
    const float* enc_b3 = (const float*)d_in[6];
    const float* dec_w1 = (const float*)d_in[7];
    const float* dec_b1 = (const float*)d_in[8];
    const float* dec_w2 = (const float*)d_in[9];
    const float* dec_b2 = (const float*)d_in[10];
    const float* dec_w3 = (const float*)d_in[11];
    const float* dec_b3 = (const float*)d_in[12];
    const float* cb     = (const float*)d_in[13];

    float* out = (float*)d_out;
    // fp32 temp tables parked in the quant region (k_dec overwrites later):
    float* P   = out;
    float* M   = out + 16384;
    float* t0  = out + 49152;
    float* v   = out + 49280;
    float* csc = out + 49408;
    // ws: loss_acc | cbW(fp32 16384) | Qbf | w2bf | w3bf  (~157 KB)
    float* ws = (float*)d_ws;
    float* loss_acc = ws;
    float* cbW = ws + 256;
    ushort_t* Qbf  = (ushort_t*)(ws + 16640);
    ushort_t* w2bf = (ushort_t*)(ws + 24832);
    ushort_t* w3bf = (ushort_t*)(ws + 33024);

    hipMemsetAsync(d_ws, 0, 16, stream);
    k_prep<<<384, 256, 0, stream>>>(cb, enc_w3, enc_b3, dec_w1, dec_w2, dec_w3,
                                    P, M, t0, v, csc, cbW, Qbf, w2bf, w3bf);
    k_encvq<<<NSAMP / 64, 256, 0, stream>>>(state, enc_w1, enc_b1, enc_w2, enc_b2,
                                            M, Qbf, t0, v, csc, P,
                                            out + OFF_CODE, loss_acc);
    k_dec<<<NSAMP / 64, 256, 0, stream>>>(out + OFF_CODE, cb, cbW,
                                          dec_b1, w2bf, dec_b2, w3bf, dec_b3,
                                          out, out + OFF_RECON);
    k_loss<<<1, 1, 0, stream>>>(loss_acc, out + OFF_LOSS);
}